// Round 15
// baseline (2115.677 us; speedup 1.0000x reference)
//
#include <hip/hip_runtime.h>
#include <hip/hip_cooperative_groups.h>

#define NB 32      // batch
#define NS 128     // src len
#define NT 128     // tgt len
#define NH 512     // hidden
#define NVS 8000   // src vocab
#define NVE 8000   // tgt vocab

typedef float fx4 __attribute__((ext_vector_type(4)));
typedef float fx2 __attribute__((ext_vector_type(2)));
typedef short bf16x8 __attribute__((ext_vector_type(8)));
typedef float f32x4 __attribute__((ext_vector_type(4)));

__device__ __forceinline__ float sigm(float x) { return 1.0f / (1.0f + expf(-x)); }

// Coherent (L1/L2-bypassing, Infinity-Cache-served) load/store for
// cross-XCD h exchange.
__device__ __forceinline__ fx4 load_cg(const float* p) {
  fx4 v;
  asm volatile("global_load_dwordx4 %0, %1, off sc0 sc1" : "=v"(v) : "v"(p));
  return v;
}
__device__ __forceinline__ void store_cg8(float* p, fx2 v) {
  asm volatile("global_store_dwordx2 %0, %1, off sc0 sc1" :: "v"(p), "v"(v) : "memory");
}

// ---------------------------------------------------------------------------
// Scan: 128 encoder + 128 decoder LSTM steps. NEW: 512 blocks x 128 threads
// (2 blocks/CU -> one block's flag-wait overlaps the other's LDS compute).
// Block g: bg=g&1 (16-batch half), mg2=g>>1 (2 m x 4 gates = 8 rows).
// Thread (r=tid>>4 in 0..7, bl=tid&15): ONE output, dot-loop text BYTE-
// IDENTICAL to the passing R5 kernel (pins the fma contraction). Cell-update
// expressions identical. Publish = 8B dwordx2 sc0sc1 + flag.
// ---------------------------------------------------------------------------
__global__ __launch_bounds__(128) void scan_kernel(
    const int* __restrict__ in_tok, const int* __restrict__ out_tok,
    const float* __restrict__ We_ih, const float* __restrict__ We_hh,
    const float* __restrict__ be_ih, const float* __restrict__ be_hh,
    const float* __restrict__ Wd_ih, const float* __restrict__ Wd_hh,
    const float* __restrict__ bd_ih, const float* __restrict__ bd_hh,
    float* __restrict__ h_buf,      // [2][NB][NH]
    float* __restrict__ enc_out,    // [NS][NB][NH]
    float* __restrict__ dec_h,      // [NT][NB][NH]
    int* __restrict__ flags)        // [512], memset 0 before launch
{
  __shared__ float W_lds[8][520];     // 8 gate rows x 512, padded
  __shared__ float h_lds[16 * 516];   // 16 b-rows, padded stride 516
  __shared__ float gbuf[8][16];       // [r][bl]
  __shared__ float c_buf[2][16];      // [m][bl] persistent cell state
  __shared__ float hstage[16][2];     // [bl][m]

  const int tid = threadIdx.x;        // 0..127
  const int g   = blockIdx.x;         // 0..511
  const int bg  = g & 1;              // which 16-batch half
  const int mg2 = g >> 1;             // 2-m group 0..255
  const int r   = tid >> 4;           // gate-row 0..7
  const int bl  = tid & 15;           // local batch
  const int b   = bg * 16 + bl;
  const int q   = r >> 1;             // gate index (i,f,g,o)
  const int i   = r & 1;              // m within slice
  const int j   = q * NH + mg2 * 2 + i;  // global gate row

  const int* f0 = flags + ((tid << 1) | bg);          // producer mg2 = tid
  const int* f1 = flags + (((tid + 128) << 1) | bg);  // producer mg2 = tid+128

  const float bias_e = be_ih[j] + be_hh[j];
  const float bias_d = bd_ih[j] + bd_hh[j];
  const float* Wcol_e = We_ih + (size_t)j * NVS;
  const float* Wcol_d = Wd_ih + (size_t)j * NVE;

  if (tid < 32) c_buf[tid >> 4][tid & 15] = 0.0f;

  // stage encoder W_hh slice: 8 rows x 512 floats (coalesced float4)
  {
    const float* Wg = We_hh;
    for (int u = tid; u < 1024; u += 128) {
      const int rr = u >> 7;               // 128 float4 per row
      const int k4 = (u & 127) << 2;
      const int jj = (rr >> 1) * NH + mg2 * 2 + (rr & 1);
      *(float4*)&W_lds[rr][k4] = *(const float4*)(Wg + (size_t)jj * NH + k4);
    }
  }
  __syncthreads();

  for (int s = 0; s < NS + NT; ++s) {
    const bool enc = (s < NS);
    if (s == NS) {  // restage decoder W_hh
      const float* Wg = Wd_hh;
      for (int u = tid; u < 1024; u += 128) {
        const int rr = u >> 7;
        const int k4 = (u & 127) << 2;
        const int jj = (rr >> 1) * NH + mg2 * 2 + (rr & 1);
        *(float4*)&W_lds[rr][k4] = *(const float4*)(Wg + (size_t)jj * NH + k4);
      }
      __syncthreads();
    }
    const int st  = enc ? s : s - NS;
    const int tok = enc ? in_tok[b * NS + st] : out_tok[b * NT + st];
    const float xp = enc ? Wcol_e[tok] : Wcol_d[tok];   // HBM gather, hidden
    const float bias = enc ? bias_e : bias_d;
    const float* Wrow = &W_lds[r][0];

    float acc = 0.0f;
    if (s > 0) {
      // wait for all 256 same-half producers of h^{s-1} (2 flags/thread)
      while (__hip_atomic_load(f0, __ATOMIC_RELAXED,
                               __HIP_MEMORY_SCOPE_AGENT) < s ||
             __hip_atomic_load(f1, __ATOMIC_RELAXED,
                               __HIP_MEMORY_SCOPE_AGENT) < s)
        __builtin_amdgcn_s_sleep(1);
      __syncthreads();
      // stage 16 x 512 h-slice into LDS via coherent dwordx4 loads
      const float* hsrc = h_buf + ((s - 1) & 1) * (NB * NH) + bg * 16 * NH;
      fx4 tmp[16];
      #pragma unroll
      for (int it = 0; it < 16; ++it)
        tmp[it] = load_cg(hsrc + ((tid + (it << 7)) << 2));
      asm volatile("s_waitcnt vmcnt(0)" ::: "memory");
      __builtin_amdgcn_sched_barrier(0);
      #pragma unroll
      for (int it = 0; it < 16; ++it) {
        const int u = tid + (it << 7);
        const int bb = u >> 7;
        const int kk = (u & 127) << 2;
        *(fx4*)&h_lds[bb * 516 + kk] = tmp[it];
      }
      __syncthreads();
      // EXACT R3/R5 inner loop (summation order preserved)
      const float* hrow = &h_lds[bl * 516];
      #pragma unroll 8
      for (int k = 0; k < NH; k += 4) {
        const float4 hv = *(const float4*)(hrow + k);
        const float4 wv = *(const float4*)(Wrow + k);
        acc += hv.x * wv.x + hv.y * wv.y + hv.z * wv.z + hv.w * wv.w;
      }
    }
    gbuf[r][bl] = acc + xp + bias;
    __syncthreads();

    if (tid < 32) {  // cell update: 2 m x 16 b (expressions identical to R5)
      const int ii = tid >> 4;
      const int bb = tid & 15;
      const float gi = gbuf[ii][bb];
      const float gf = gbuf[2 + ii][bb];
      const float gg = gbuf[4 + ii][bb];
      const float go = gbuf[6 + ii][bb];
      const float co = c_buf[ii][bb];
      const float cn = sigm(gf) * co + sigm(gi) * tanhf(gg);
      const float hn = sigm(go) * tanhf(cn);
      c_buf[ii][bb] = cn;
      hstage[bb][ii] = hn;
    }
    __syncthreads();
    if (tid < 16) {  // packed 8B coherent store of this block's h chunk
      const fx2 hv = *(const fx2*)&hstage[tid][0];
      const int bglob = bg * 16 + tid;
      store_cg8(h_buf + (s & 1) * (NB * NH) + bglob * NH + mg2 * 2, hv);
      float* dst = enc ? (enc_out + ((size_t)st * NB + bglob) * NH + mg2 * 2)
                       : (dec_h  + ((size_t)st * NB + bglob) * NH + mg2 * 2);
      *(fx2*)dst = hv;
    }
    asm volatile("s_waitcnt vmcnt(0)" ::: "memory");  // drain h stores
    __syncthreads();
    if (tid == 0)
      __hip_atomic_store(&flags[g], s + 1, __ATOMIC_RELAXED,
                         __HIP_MEMORY_SCOPE_AGENT);
  }
}

// ---------------------------------------------------------------------------
// 64x64-tile fp32 GEMM (small batched attention GEMMs). Steps 3/5 stay fp32
// so the attention weights are bit-identical to the passing builds.
// ---------------------------------------------------------------------------
template<int TRANSB, int CSWAP, int ACT>
__global__ __launch_bounds__(256) void gemm64(
    const float* __restrict__ A, const float* __restrict__ Bm,
    float* __restrict__ C, const float* __restrict__ bias,
    const float* __restrict__ A2, int ksplit,
    int M, int N, int K, int lda, int ldb, int ldc,
    long batchA, long batchB, long batchC)
{
  __shared__ float As[16][68];
  __shared__ float Bs[16][68];
  const int z = blockIdx.z;
  A += (long)z * batchA;
  if (A2 != nullptr) A2 += (long)z * batchA;
  Bm += (long)z * batchB;
  C  += (long)z * batchC;
  const int m0 = blockIdx.y << 6;
  const int n0 = blockIdx.x << 6;
  const int tid = threadIdx.x;
  const int tx = tid & 15;
  const int ty = tid >> 4;
  float acc[4][4] = {};

  for (int k0 = 0; k0 < K; k0 += 16) {
    {
      const int mrow = tid >> 2;
      const int kcq = (tid & 3) << 2;
      const float* base = A;
      int keff = k0;
      if (A2 != nullptr && k0 >= ksplit) { base = A2; keff = k0 - ksplit; }
      const float4 v = *(const float4*)(base + (long)(m0 + mrow) * lda + keff + kcq);
      As[kcq + 0][mrow] = v.x; As[kcq + 1][mrow] = v.y;
      As[kcq + 2][mrow] = v.z; As[kcq + 3][mrow] = v.w;
    }
    if (TRANSB == 0) {
      const int nrow = tid >> 2;
      const int kcq = (tid & 3) << 2;
      const float4 v = *(const float4*)(Bm + (long)(n0 + nrow) * ldb + k0 + kcq);
      Bs[kcq + 0][nrow] = v.x; Bs[kcq + 1][nrow] = v.y;
      Bs[kcq + 2][nrow] = v.z; Bs[kcq + 3][nrow] = v.w;
    } else {
      const int krow = tid >> 4;
      const int nc = (tid & 15) << 2;
      const float4 v = *(const float4*)(Bm + (long)(k0 + krow) * ldb + n0 + nc);
      *(float4*)&Bs[krow][nc] = v;
    }
    __syncthreads();
    #pragma unroll
    for (int kk = 0; kk < 16; ++kk) {
      const float4 a4 = *(const float4*)&As[kk][ty << 2];
      const float4 b4 = *(const float4*)&Bs[kk][tx << 2];
      const float a[4]  = {a4.x, a4.y, a4.z, a4.w};
      const float bv[4] = {b4.x, b4.y, b4.z, b4.w};
      #pragma unroll
      for (int ii = 0; ii < 4; ++ii)
        #pragma unroll
        for (int jj = 0; jj < 4; ++jj)
          acc[ii][jj] = fmaf(a[ii], bv[jj], acc[ii][jj]);
    }
    __syncthreads();
  }

  const int n = n0 + (tx << 2);
  float4 bb4 = {0.f, 0.f, 0.f, 0.f};
  if (bias) { bb4.x = bias[n]; bb4.y = bias[n + 1]; bb4.z = bias[n + 2]; bb4.w = bias[n + 3]; }
  #pragma unroll
  for (int ii = 0; ii < 4; ++ii) {
    const int mrow = m0 + (ty << 2) + ii;
    float4 o;
    o.x = acc[ii][0] + bb4.x; o.y = acc[ii][1] + bb4.y;
    o.z = acc[ii][2] + bb4.z; o.w = acc[ii][3] + bb4.w;
    if (ACT == 1) { o.x = tanhf(o.x); o.y = tanhf(o.y); o.z = tanhf(o.z); o.w = tanhf(o.w); }
    long orow = mrow;
    if (CSWAP) orow = (long)(mrow & (NB - 1)) * NT + (mrow >> 5);
    *(float4*)(C + orow * (long)ldc + n) = o;
  }
}

// ---------------------------------------------------------------------------
// fp32 -> (bf16_hi, bf16_lo) split, RNE both. lo = x - float(hi).
// ---------------------------------------------------------------------------
__global__ __launch_bounds__(256) void split_bf16(
    const float* __restrict__ x, unsigned short* __restrict__ hi,
    unsigned short* __restrict__ lo, int n4)
{
  for (int i = blockIdx.x * 256 + threadIdx.x; i < n4; i += gridDim.x * 256) {
    const float4 v = ((const float4*)x)[i];
    float f[4] = {v.x, v.y, v.z, v.w};
    unsigned short hh[4], ll[4];
    #pragma unroll
    for (int jj = 0; jj < 4; ++jj) {
      const unsigned int u = __float_as_uint(f[jj]);
      const unsigned int r = (u + 0x7FFFu + ((u >> 16) & 1u)) >> 16;
      hh[jj] = (unsigned short)r;
      const float hf = __uint_as_float(r << 16);
      const float lf = f[jj] - hf;
      const unsigned int u2 = __float_as_uint(lf);
      const unsigned int r2 = (u2 + 0x7FFFu + ((u2 >> 16) & 1u)) >> 16;
      ll[jj] = (unsigned short)r2;
    }
    ushort4 hv, lv;
    hv.x = hh[0]; hv.y = hh[1]; hv.z = hh[2]; hv.w = hh[3];
    lv.x = ll[0]; lv.y = ll[1]; lv.z = ll[2]; lv.w = ll[3];
    ((ushort4*)hi)[i] = hv;
    ((ushort4*)lo)[i] = lv;
  }
}

// ---------------------------------------------------------------------------
// Generic split-bf16 MFMA GEMM: C[m][n] = A[m]·B[n] + bias[n], 3-product
// (hi·hi + hi·lo + lo·hi), fp32 accum. Optional concat-A (A2/ksplit),
// optional tanh, OUT: 0 = fp32 C, 2 = bf16 hi/lo split outputs.
// Block 256 thr = 4 m-stacked waves; tile 128m x 64n; B staged in LDS.
// ---------------------------------------------------------------------------
template<int ACT, int OUT>
__global__ __launch_bounds__(256) void gemm_mfma(
    const unsigned short* __restrict__ Ahi, const unsigned short* __restrict__ Alo,
    const unsigned short* __restrict__ A2hi, const unsigned short* __restrict__ A2lo,
    int ksplit,
    const unsigned short* __restrict__ Bhi, const unsigned short* __restrict__ Blo,
    float* __restrict__ C, unsigned short* __restrict__ outHi,
    unsigned short* __restrict__ outLo, const float* __restrict__ bias,
    int K, int lda, int ldb, int ldc)
{
  __shared__ unsigned short BsH[64 * 32];
  __shared__ unsigned short BsL[64 * 32];
  const int tid  = threadIdx.x;
  const int wid  = tid >> 6;
  const int lane = tid & 63;
  const int l15  = lane & 15;
  const int kg   = lane >> 4;
  const int m0   = (blockIdx.y << 7) + (wid << 5);
  const int n0   = blockIdx.x << 6;
  const int srow = tid >> 2;
  const int scol = (tid & 3) << 3;

  f32x4 acc[2][4];
  #pragma unroll
  for (int fm = 0; fm < 2; ++fm)
    #pragma unroll
    for (int fn = 0; fn < 4; ++fn)
      acc[fm][fn] = (f32x4){0.f, 0.f, 0.f, 0.f};

  for (int k0 = 0; k0 < K; k0 += 32) {
    __syncthreads();
    *(bf16x8*)&BsH[srow * 32 + scol] =
        *(const bf16x8*)(Bhi + (size_t)(n0 + srow) * ldb + k0 + scol);
    *(bf16x8*)&BsL[srow * 32 + scol] =
        *(const bf16x8*)(Blo + (size_t)(n0 + srow) * ldb + k0 + scol);
    __syncthreads();

    const unsigned short* baseH = Ahi;
    const unsigned short* baseL = Alo;
    int keff = k0;
    if (A2hi != nullptr && k0 >= ksplit) {
      baseH = A2hi; baseL = A2lo; keff = k0 - ksplit;
    }
    bf16x8 ah[2], al[2];
    #pragma unroll
    for (int fm = 0; fm < 2; ++fm) {
      const size_t ro = (size_t)(m0 + (fm << 4) + l15) * lda + keff + (kg << 3);
      ah[fm] = *(const bf16x8*)(baseH + ro);
      al[fm] = *(const bf16x8*)(baseL + ro);
    }
    #pragma unroll
    for (int fm = 0; fm < 2; ++fm) {
      #pragma unroll
      for (int fn = 0; fn < 4; ++fn) {
        const bf16x8 bh  = *(const bf16x8*)&BsH[(((fn << 4) + l15) << 5) + (kg << 3)];
        const bf16x8 blv = *(const bf16x8*)&BsL[(((fn << 4) + l15) << 5) + (kg << 3)];
        acc[fm][fn] = __builtin_amdgcn_mfma_f32_16x16x32_bf16(
            ah[fm], bh, acc[fm][fn], 0, 0, 0);
        acc[fm][fn] = __builtin_amdgcn_mfma_f32_16x16x32_bf16(
            ah[fm], blv, acc[fm][fn], 0, 0, 0);
        acc[fm][fn] = __builtin_amdgcn_mfma_f32_16x16x32_bf16(
            al[fm], bh, acc[fm][fn], 0, 0, 0);
      }
    }
  }

  // epilogue: D col=l15, row=kg*4+reg (m89-verified)
  #pragma unroll
  for (int fm = 0; fm < 2; ++fm) {
    #pragma unroll
    for (int fn = 0; fn < 4; ++fn) {
      const int n = n0 + (fn << 4) + l15;
      const float bb = bias ? bias[n] : 0.0f;
      #pragma unroll
      for (int rg = 0; rg < 4; ++rg) {
        const int m = m0 + (fm << 4) + (kg << 2) + rg;
        float v = acc[fm][fn][rg] + bb;
        if (ACT == 1) v = tanhf(v);
        if (OUT == 2) {
          const unsigned int u = __float_as_uint(v);
          const unsigned int rv = (u + 0x7FFFu + ((u >> 16) & 1u)) >> 16;
          const float hf = __uint_as_float(rv << 16);
          const float lf = v - hf;
          const unsigned int u2 = __float_as_uint(lf);
          const unsigned int rl = (u2 + 0x7FFFu + ((u2 >> 16) & 1u)) >> 16;
          outHi[(size_t)m * ldc + n] = (unsigned short)rv;
          outLo[(size_t)m * ldc + n] = (unsigned short)rl;
        } else {
          C[(size_t)m * ldc + n] = v;
        }
      }
    }
  }
}

// ---------------------------------------------------------------------------
// Split-bf16 MFMA logits GEMM (proven R13 kernel, unchanged).
// C[(m&31)*NT+(m>>5)][n] = hid[m]·W2[n] + b2[n].
// ---------------------------------------------------------------------------
__global__ __launch_bounds__(256) void gemm_mfma_logits(
    const unsigned short* __restrict__ Ahi, const unsigned short* __restrict__ Alo,
    const unsigned short* __restrict__ Bhi, const unsigned short* __restrict__ Blo,
    float* __restrict__ C, const float* __restrict__ bias)
{
  __shared__ unsigned short BsH[64 * 32];   // [n-local][k-local]
  __shared__ unsigned short BsL[64 * 32];
  const int tid  = threadIdx.x;
  const int wid  = tid >> 6;        // wave 0..3 (m-stacked)
  const int lane = tid & 63;
  const int l15  = lane & 15;
  const int kg   = lane >> 4;       // 0..3
  const int m0   = (blockIdx.y << 7) + (wid << 5);  // wave's 32-row m base
  const int n0   = blockIdx.x << 6;

  const size_t aoff = (size_t)(m0 + l15) * NH + (kg << 3);
  const int srow = tid >> 2;        // staging: 64 rows, 4 thr/row
  const int scol = (tid & 3) << 3;  // 8-ushort chunks

  f32x4 acc[2][4];
  #pragma unroll
  for (int fm = 0; fm < 2; ++fm)
    #pragma unroll
    for (int fn = 0; fn < 4; ++fn)
      acc[fm][fn] = (f32x4){0.f, 0.f, 0.f, 0.f};

  for (int k0 = 0; k0 < NH; k0 += 32) {
    __syncthreads();  // prior iteration's LDS reads complete
    *(bf16x8*)&BsH[srow * 32 + scol] =
        *(const bf16x8*)(Bhi + (size_t)(n0 + srow) * NH + k0 + scol);
    *(bf16x8*)&BsL[srow * 32 + scol] =
        *(const bf16x8*)(Blo + (size_t)(n0 + srow) * NH + k0 + scol);
    __syncthreads();

    bf16x8 ah[2], al[2];
    #pragma unroll
    for (int fm = 0; fm < 2; ++fm) {
      ah[fm] = *(const bf16x8*)(Ahi + aoff + (size_t)(fm << 4) * NH + k0);
      al[fm] = *(const bf16x8*)(Alo + aoff + (size_t)(fm << 4) * NH + k0);
    }
    #pragma unroll
    for (int fm = 0; fm < 2; ++fm) {
      #pragma unroll
      for (int fn = 0; fn < 4; ++fn) {
        const bf16x8 bh  = *(const bf16x8*)&BsH[(((fn << 4) + l15) << 5) + (kg << 3)];
        const bf16x8 blv = *(const bf16x8*)&BsL[(((fn << 4) + l15) << 5) + (kg << 3)];
        acc[fm][fn] = __builtin_amdgcn_mfma_f32_16x16x32_bf16(
            ah[fm], bh, acc[fm][fn], 0, 0, 0);
        acc[fm][fn] = __builtin_amdgcn_mfma_f32_16x16x32_bf16(
            ah[fm], blv, acc[fm][fn], 0, 0, 0);
        acc[fm][fn] = __builtin_amdgcn_mfma_f32_16x16x32_bf16(
            al[fm], bh, acc[fm][fn], 0, 0, 0);
      }
    }
  }

  // epilogue: D col=l15, row=kg*4+reg; CSWAP (t*B+b) -> (b*T+t)
  #pragma unroll
  for (int fm = 0; fm < 2; ++fm) {
    #pragma unroll
    for (int fn = 0; fn < 4; ++fn) {
      const int n = n0 + (fn << 4) + l15;
      const float bb = bias[n];
      #pragma unroll
      for (int rg = 0; rg < 4; ++rg) {
        const int m = m0 + (fm << 4) + (kg << 2) + rg;
        const long orow = (long)(m & (NB - 1)) * NT + (m >> 5);
        C[orow * NVE + n] = acc[fm][fn][rg] + bb;
      }
    }
  }
}

// softmax over S=128 per (t,b) row, in place
__global__ __launch_bounds__(128) void softmax_s(float* __restrict__ sc) {
  const long row = blockIdx.x;
  float* p = sc + row * NS;
  const float x = p[threadIdx.x];
  float mx = x;
  for (int o = 32; o; o >>= 1) mx = fmaxf(mx, __shfl_xor(mx, o));
  __shared__ float r0[2], r1[2];
  const int w = threadIdx.x >> 6;
  if ((threadIdx.x & 63) == 0) r0[w] = mx;
  __syncthreads();
  mx = fmaxf(r0[0], r0[1]);
  const float e = expf(x - mx);
  float sum = e;
  for (int o = 32; o; o >>= 1) sum += __shfl_xor(sum, o);
  if ((threadIdx.x & 63) == 0) r1[w] = sum;
  __syncthreads();
  sum = r1[0] + r1[1];
  p[threadIdx.x] = e / sum;
}

// softmax over VE=8000 per (b,t) row of d_out, in place
__global__ __launch_bounds__(256) void softmax_v(float* __restrict__ out) {
  const long row = blockIdx.x;
  float* p = out + row * NVE;
  float v[32];
  float mx = -1e30f;
  #pragma unroll
  for (int it = 0; it < 32; ++it) {
    const int idx = (it << 8) + threadIdx.x;
    v[it] = (idx < NVE) ? p[idx] : -1e30f;
    mx = fmaxf(mx, v[it]);
  }
  for (int o = 32; o; o >>= 1) mx = fmaxf(mx, __shfl_xor(mx, o));
  __shared__ float red[4], red2[4];
  const int w = threadIdx.x >> 6;
  if ((threadIdx.x & 63) == 0) red[w] = mx;
  __syncthreads();
  mx = fmaxf(fmaxf(red[0], red[1]), fmaxf(red[2], red[3]));
  float sum = 0.0f;
  #pragma unroll
  for (int it = 0; it < 32; ++it) {
    const int idx = (it << 8) + threadIdx.x;
    if (idx < NVE) { v[it] = expf(v[it] - mx); sum += v[it]; }
  }
  for (int o = 32; o; o >>= 1) sum += __shfl_xor(sum, o);
  if ((threadIdx.x & 63) == 0) red2[w] = sum;
  __syncthreads();
  sum = red2[0] + red2[1] + red2[2] + red2[3];
  const float inv = 1.0f / sum;
  #pragma unroll
  for (int it = 0; it < 32; ++it) {
    const int idx = (it << 8) + threadIdx.x;
    if (idx < NVE) p[idx] = v[it] * inv;
  }
}

extern "C" void kernel_launch(void* const* d_in, const int* in_sizes, int n_in,
                              void* d_out, int out_size, void* d_ws, size_t ws_size,
                              hipStream_t stream) {
  const int*   in_tok = (const int*)d_in[0];
  const int*   out_tok = (const int*)d_in[1];
  const float* Wa    = (const float*)d_in[2];
  const float* ba    = (const float*)d_in[3];
  const float* W1    = (const float*)d_in[4];
  const float* b1    = (const float*)d_in[5];
  const float* W2    = (const float*)d_in[6];
  const float* b2    = (const float*)d_in[7];
  const float* We_ih = (const float*)d_in[8];
  const float* We_hh = (const float*)d_in[9];
  const float* be_ih = (const float*)d_in[10];
  const float* be_hh = (const float*)d_in[11];
  const float* Wd_ih = (const float*)d_in[12];
  const float* Wd_hh = (const float*)d_in[13];
  const float* bd_ih = (const float*)d_in[14];
  const float* bd_hh = (const float*)d_in[15];

  float* ws      = (float*)d_ws;
  float* h_buf   = ws;                 // [0, 32768)
  float* enc_out = ws + 32768;         // [32768, 2129920)
  float* dec_h   = ws + 2129920;       // [2129920, 4227072)
  float* proj    = ws + 4227072;       // [4227072, 6324224)
  float* scores  = ws + 6324224;       // [6324224, 6848512)
  float* ctx     = ws + 6848512;       // [6848512, 8945664)
  // spare (old hid region): [8945664, 11042816)
  int*   flags   = (int*)(ws + 11042816);  // 512 ints
  float* out     = (float*)d_out;

  // bf16 hi/lo aliases, sequenced so no live ranges overlap:
  unsigned short* eo_hi  = (unsigned short*)(ws + 8945664);            // spare
  unsigned short* eo_lo  = (unsigned short*)(ws + 8945664 + 1048576);
  unsigned short* wa_hi  = (unsigned short*)(ws + 6324224);            // scores (pre-step3)
  unsigned short* wa_lo  = (unsigned short*)(ws + 6324224 + 131072);
  unsigned short* w1_hi  = (unsigned short*)(ws + 4227072);            // proj (post-step3)
  unsigned short* w1_lo  = (unsigned short*)(ws + 4227072 + 262144);
  unsigned short* dh_hi  = (unsigned short*)(ws + 32768);              // enc_out (post-step5)
  unsigned short* dh_lo  = (unsigned short*)(ws + 32768 + 1048576);
  unsigned short* cx_hi  = (unsigned short*)(ws + 2129920);            // dec_h (post dh-split)
  unsigned short* cx_lo  = (unsigned short*)(ws + 2129920 + 1048576);
  unsigned short* hid_hi = (unsigned short*)(ws + 6848512);            // ctx (post cx-split)
  unsigned short* hid_lo = (unsigned short*)(ws + 6848512 + 1048576);
  unsigned short* w2_hi  = (unsigned short*)(ws + 8945664);            // spare (post-step6)
  unsigned short* w2_lo  = (unsigned short*)(ws + 32768);              // enc_out (post-step6)

  (void)hipMemsetAsync((void*)flags, 0, 512 * sizeof(int), stream);

  // 1. encoder + decoder-LSTM scan (512 blocks x 128 thr, 2 blocks/CU)
  {
    void* args[14];
    args[0] = (void*)&in_tok; args[1] = (void*)&out_tok;
    args[2] = (void*)&We_ih;  args[3] = (void*)&We_hh;
    args[4] = (void*)&be_ih;  args[5] = (void*)&be_hh;
    args[6] = (void*)&Wd_ih;  args[7] = (void*)&Wd_hh;
    args[8] = (void*)&bd_ih;  args[9] = (void*)&bd_hh;
    args[10] = (void*)&h_buf; args[11] = (void*)&enc_out; args[12] = (void*)&dec_h;
    args[13] = (void*)&flags;
    (void)hipLaunchCooperativeKernel((void*)scan_kernel, dim3(512), dim3(128), args, 0, stream);
  }

  // 2a. splits for proj GEMM
  split_bf16<<<dim3(2048), 256, 0, stream>>>(enc_out, eo_hi, eo_lo, 524288);
  split_bf16<<<dim3(512), 256, 0, stream>>>(Wa, wa_hi, wa_lo, 65536);

  // 2b. proj = enc_out @ Wa^T + ba   [4096,512] K=512 (split-bf16 MFMA)
  gemm_mfma<0, 0><<<dim3(8, 32), 256, 0, stream>>>(
      eo_hi, eo_lo, nullptr, nullptr, 1 << 30,
      wa_hi, wa_lo, proj, nullptr, nullptr, ba,
      512, 512, 512, 512);

  // 3. scores[t,b,s] = dec_h . proj_enc (batched over b)   M=T,N=S,K=H (fp32)
  gemm64<0,0,0><<<dim3(2,2,NB), 256, 0, stream>>>(
      dec_h, proj, scores, nullptr, nullptr, 1 << 30,
      NT, NS, NH, NB * NH, NB * NH, NB * NS,
      (long)NH, (long)NH, (long)NS);

  // 4. softmax over s
  softmax_s<<<dim3(NT * NB), 128, 0, stream>>>(scores);

  // 4b. split W1 (proj region free after step 3)
  split_bf16<<<dim3(1024), 256, 0, stream>>>(W1, w1_hi, w1_lo, 131072);

  // 5. context[t,b,h] = w @ enc_out (batched over b, B is [K][N])  (fp32)
  gemm64<1,0,0><<<dim3(8,2,NB), 256, 0, stream>>>(
      scores, enc_out, ctx, nullptr, nullptr, 1 << 30,
      NT, NH, NS, NB * NS, NB * NH, NB * NH,
      (long)NS, (long)NH, (long)NH);

  // 5b. split dec_h (into enc_out region) then ctx (into dec_h region)
  split_bf16<<<dim3(2048), 256, 0, stream>>>(dec_h, dh_hi, dh_lo, 524288);
  split_bf16<<<dim3(2048), 256, 0, stream>>>(ctx, cx_hi, cx_lo, 524288);

  // 6. hid = tanh(concat(dec_h, ctx) @ W1^T + b1) -> bf16 hi/lo (MFMA)
  gemm_mfma<1, 2><<<dim3(8, 32), 256, 0, stream>>>(
      dh_hi, dh_lo, cx_hi, cx_lo, 512,
      w1_hi, w1_lo, nullptr, hid_hi, hid_lo, b1,
      1024, 512, 1024, 512);

  // 6b. split W2 (spare + enc_out regions free after step 6)
  split_bf16<<<dim3(2048), 256, 0, stream>>>(W2, w2_hi, w2_lo, 1024000);

  // 7. logits = hid @ W2^T + b2 -> d_out[b][t][v]  via split-bf16 MFMA
  gemm_mfma_logits<<<dim3(125, 32), 256, 0, stream>>>(
      hid_hi, hid_lo, w2_hi, w2_lo, out, b2);

  // 8. softmax over vocab, in place on d_out
  softmax_v<<<dim3(NB * NT), 256, 0, stream>>>(out);
}

// Round 16
// 1946.469 us; speedup vs baseline: 1.0869x; 1.0869x over previous
//
#include <hip/hip_runtime.h>
#include <hip/hip_cooperative_groups.h>

#define NB 32      // batch
#define NS 128     // src len
#define NT 128     // tgt len
#define NH 512     // hidden
#define NVS 8000   // src vocab
#define NVE 8000   // tgt vocab

typedef float fx4 __attribute__((ext_vector_type(4)));
typedef short bf16x8 __attribute__((ext_vector_type(8)));
typedef float f32x4 __attribute__((ext_vector_type(4)));

__device__ __forceinline__ float sigm(float x) { return 1.0f / (1.0f + expf(-x)); }

// Coherent (L1/L2-bypassing, Infinity-Cache-served) 16B load/store for
// cross-XCD h exchange.
__device__ __forceinline__ fx4 load_cg(const float* p) {
  fx4 v;
  asm volatile("global_load_dwordx4 %0, %1, off sc0 sc1" : "=v"(v) : "v"(p));
  return v;
}
__device__ __forceinline__ void store_cg(float* p, fx4 v) {
  asm volatile("global_store_dwordx4 %0, %1, off sc0 sc1" :: "v"(p), "v"(v) : "memory");
}

// ---------------------------------------------------------------------------
// Scan: VERBATIM R5 kernel (measured PASS: absmax 9.54e-7, ~1690 us).
// DO NOT TOUCH: dot-loop text/structure pins the rounding that passes.
// Structural floor: 1024 ds_read_b128/CU/step x ~12cyc ~ 5.9us vs 6.6us
// measured; all read-reducing decompositions shift fma contraction ->
// absmax >= 5.7e-6 (R8/R9/R10); 2-blocks/CU overlap regressed (R15).
// ---------------------------------------------------------------------------
__global__ __launch_bounds__(256) void scan_kernel(
    const int* __restrict__ in_tok, const int* __restrict__ out_tok,
    const float* __restrict__ We_ih, const float* __restrict__ We_hh,
    const float* __restrict__ be_ih, const float* __restrict__ be_hh,
    const float* __restrict__ Wd_ih, const float* __restrict__ Wd_hh,
    const float* __restrict__ bd_ih, const float* __restrict__ bd_hh,
    float* __restrict__ h_buf,      // [2][NB][NH]
    float* __restrict__ enc_out,    // [NS][NB][NH]
    float* __restrict__ dec_h,      // [NT][NB][NH]
    int* __restrict__ flags)        // [256], memset 0 before launch
{
  __shared__ float W_lds[16][520];    // 16 gate rows x 512, padded
  __shared__ float h_lds[16 * 516];   // 16 b-rows, padded stride 516
  __shared__ float gbuf[16][16];      // [r][bl]
  __shared__ float c_buf[4][16];      // [m][bl] persistent cell state
  __shared__ float hstage[16][4];     // [bl][m]

  const int tid = threadIdx.x;
  const int g   = blockIdx.x;
  const int bg  = g & 1;        // which 16-batch half
  const int mg  = g >> 1;       // m-group 0..127
  const int r   = tid >> 4;     // gate-row 0..15
  const int bl  = tid & 15;     // local batch
  const int b   = bg * 16 + bl;
  const int q   = r >> 2;       // gate index (i,f,g,o)
  const int i   = r & 3;        // m within slice
  const int j   = q * NH + mg * 4 + i;  // global gate row

  const float bias_e = be_ih[j] + be_hh[j];
  const float bias_d = bd_ih[j] + bd_hh[j];
  const float* Wcol_e = We_ih + (size_t)j * NVS;
  const float* Wcol_d = Wd_ih + (size_t)j * NVE;

  if (tid < 64) c_buf[tid >> 4][tid & 15] = 0.0f;

  // stage encoder W_hh slice: 16 rows x 512 floats (coalesced float4)
  {
    const float* Wg = We_hh;
    for (int u = tid; u < 2048; u += 256) {
      const int rr = u >> 7;               // 128 float4 per row
      const int k4 = (u & 127) << 2;
      const int jj = (rr >> 2) * NH + mg * 4 + (rr & 3);
      *(float4*)&W_lds[rr][k4] = *(const float4*)(Wg + (size_t)jj * NH + k4);
    }
  }
  __syncthreads();

  for (int s = 0; s < NS + NT; ++s) {
    const bool enc = (s < NS);
    if (s == NS) {  // restage decoder W_hh
      const float* Wg = Wd_hh;
      for (int u = tid; u < 2048; u += 256) {
        const int rr = u >> 7;
        const int k4 = (u & 127) << 2;
        const int jj = (rr >> 2) * NH + mg * 4 + (rr & 3);
        *(float4*)&W_lds[rr][k4] = *(const float4*)(Wg + (size_t)jj * NH + k4);
      }
      __syncthreads();
    }
    const int st  = enc ? s : s - NS;
    const int tok = enc ? in_tok[b * NS + st] : out_tok[b * NT + st];
    const float xp = enc ? Wcol_e[tok] : Wcol_d[tok];   // HBM gather, hidden
    const float bias = enc ? bias_e : bias_d;
    const float* Wrow = &W_lds[r][0];

    float acc = 0.0f;
    if (s > 0) {
      // wait for all 128 same-half producers of h^{s-1}
      if (tid < 128) {
        const int idx = (tid << 1) | bg;
        while (__hip_atomic_load(&flags[idx], __ATOMIC_RELAXED,
                                 __HIP_MEMORY_SCOPE_AGENT) < s)
          __builtin_amdgcn_s_sleep(1);
      }
      __syncthreads();
      // stage 16 x 512 h-slice into LDS via coherent dwordx4 loads
      const float* hsrc = h_buf + ((s - 1) & 1) * (NB * NH) + bg * 16 * NH;
      fx4 tmp[8];
      #pragma unroll
      for (int it = 0; it < 8; ++it)
        tmp[it] = load_cg(hsrc + ((tid + (it << 8)) << 2));
      asm volatile("s_waitcnt vmcnt(0)" ::: "memory");
      __builtin_amdgcn_sched_barrier(0);
      #pragma unroll
      for (int it = 0; it < 8; ++it) {
        const int u = tid + (it << 8);
        const int bb = u >> 7;
        const int kk = (u & 127) << 2;
        *(fx4*)&h_lds[bb * 516 + kk] = tmp[it];
      }
      __syncthreads();
      // EXACT R3 inner loop (summation order preserved)
      const float* hrow = &h_lds[bl * 516];
      #pragma unroll 8
      for (int k = 0; k < NH; k += 4) {
        const float4 hv = *(const float4*)(hrow + k);
        const float4 wv = *(const float4*)(Wrow + k);
        acc += hv.x * wv.x + hv.y * wv.y + hv.z * wv.z + hv.w * wv.w;
      }
    }
    gbuf[r][bl] = acc + xp + bias;
    __syncthreads();

    if (tid < 64) {  // cell update: 4 m x 16 b
      const int ii = tid >> 4;
      const int bb = tid & 15;
      const float gi = gbuf[ii][bb];
      const float gf = gbuf[4 + ii][bb];
      const float gg = gbuf[8 + ii][bb];
      const float go = gbuf[12 + ii][bb];
      const float co = c_buf[ii][bb];
      const float cn = sigm(gf) * co + sigm(gi) * tanhf(gg);
      const float hn = sigm(go) * tanhf(cn);
      c_buf[ii][bb] = cn;
      hstage[bb][ii] = hn;
    }
    __syncthreads();
    if (tid < 16) {  // packed 16B coherent store of this block's h chunk
      const fx4 hv = *(const fx4*)&hstage[tid][0];
      const int bglob = bg * 16 + tid;
      store_cg(h_buf + (s & 1) * (NB * NH) + bglob * NH + mg * 4, hv);
      float* dst = enc ? (enc_out + ((size_t)st * NB + bglob) * NH + mg * 4)
                       : (dec_h  + ((size_t)st * NB + bglob) * NH + mg * 4);
      *(fx4*)dst = hv;
    }
    asm volatile("s_waitcnt vmcnt(0)" ::: "memory");  // wave 0 drains h stores
    __syncthreads();
    if (tid == 0)
      __hip_atomic_store(&flags[g], s + 1, __ATOMIC_RELAXED,
                         __HIP_MEMORY_SCOPE_AGENT);
  }
}

// ---------------------------------------------------------------------------
// 64x64-tile fp32 GEMM (small batched attention GEMMs). Steps 3/5 stay fp32
// so the attention weights are bit-identical to the passing builds.
// ---------------------------------------------------------------------------
template<int TRANSB, int CSWAP, int ACT>
__global__ __launch_bounds__(256) void gemm64(
    const float* __restrict__ A, const float* __restrict__ Bm,
    float* __restrict__ C, const float* __restrict__ bias,
    const float* __restrict__ A2, int ksplit,
    int M, int N, int K, int lda, int ldb, int ldc,
    long batchA, long batchB, long batchC)
{
  __shared__ float As[16][68];
  __shared__ float Bs[16][68];
  const int z = blockIdx.z;
  A += (long)z * batchA;
  if (A2 != nullptr) A2 += (long)z * batchA;
  Bm += (long)z * batchB;
  C  += (long)z * batchC;
  const int m0 = blockIdx.y << 6;
  const int n0 = blockIdx.x << 6;
  const int tid = threadIdx.x;
  const int tx = tid & 15;
  const int ty = tid >> 4;
  float acc[4][4] = {};

  for (int k0 = 0; k0 < K; k0 += 16) {
    {
      const int mrow = tid >> 2;
      const int kcq = (tid & 3) << 2;
      const float* base = A;
      int keff = k0;
      if (A2 != nullptr && k0 >= ksplit) { base = A2; keff = k0 - ksplit; }
      const float4 v = *(const float4*)(base + (long)(m0 + mrow) * lda + keff + kcq);
      As[kcq + 0][mrow] = v.x; As[kcq + 1][mrow] = v.y;
      As[kcq + 2][mrow] = v.z; As[kcq + 3][mrow] = v.w;
    }
    if (TRANSB == 0) {
      const int nrow = tid >> 2;
      const int kcq = (tid & 3) << 2;
      const float4 v = *(const float4*)(Bm + (long)(n0 + nrow) * ldb + k0 + kcq);
      Bs[kcq + 0][nrow] = v.x; Bs[kcq + 1][nrow] = v.y;
      Bs[kcq + 2][nrow] = v.z; Bs[kcq + 3][nrow] = v.w;
    } else {
      const int krow = tid >> 4;
      const int nc = (tid & 15) << 2;
      const float4 v = *(const float4*)(Bm + (long)(k0 + krow) * ldb + n0 + nc);
      *(float4*)&Bs[krow][nc] = v;
    }
    __syncthreads();
    #pragma unroll
    for (int kk = 0; kk < 16; ++kk) {
      const float4 a4 = *(const float4*)&As[kk][ty << 2];
      const float4 b4 = *(const float4*)&Bs[kk][tx << 2];
      const float a[4]  = {a4.x, a4.y, a4.z, a4.w};
      const float bv[4] = {b4.x, b4.y, b4.z, b4.w};
      #pragma unroll
      for (int ii = 0; ii < 4; ++ii)
        #pragma unroll
        for (int jj = 0; jj < 4; ++jj)
          acc[ii][jj] = fmaf(a[ii], bv[jj], acc[ii][jj]);
    }
    __syncthreads();
  }

  const int n = n0 + (tx << 2);
  float4 bb4 = {0.f, 0.f, 0.f, 0.f};
  if (bias) { bb4.x = bias[n]; bb4.y = bias[n + 1]; bb4.z = bias[n + 2]; bb4.w = bias[n + 3]; }
  #pragma unroll
  for (int ii = 0; ii < 4; ++ii) {
    const int mrow = m0 + (ty << 2) + ii;
    float4 o;
    o.x = acc[ii][0] + bb4.x; o.y = acc[ii][1] + bb4.y;
    o.z = acc[ii][2] + bb4.z; o.w = acc[ii][3] + bb4.w;
    if (ACT == 1) { o.x = tanhf(o.x); o.y = tanhf(o.y); o.z = tanhf(o.z); o.w = tanhf(o.w); }
    long orow = mrow;
    if (CSWAP) orow = (long)(mrow & (NB - 1)) * NT + (mrow >> 5);
    *(float4*)(C + orow * (long)ldc + n) = o;
  }
}

// ---------------------------------------------------------------------------
// fp32 -> (bf16_hi, bf16_lo) split, RNE both. lo = x - float(hi).
// ---------------------------------------------------------------------------
__global__ __launch_bounds__(256) void split_bf16(
    const float* __restrict__ x, unsigned short* __restrict__ hi,
    unsigned short* __restrict__ lo, int n4)
{
  for (int i = blockIdx.x * 256 + threadIdx.x; i < n4; i += gridDim.x * 256) {
    const float4 v = ((const float4*)x)[i];
    float f[4] = {v.x, v.y, v.z, v.w};
    unsigned short hh[4], ll[4];
    #pragma unroll
    for (int jj = 0; jj < 4; ++jj) {
      const unsigned int u = __float_as_uint(f[jj]);
      const unsigned int r = (u + 0x7FFFu + ((u >> 16) & 1u)) >> 16;
      hh[jj] = (unsigned short)r;
      const float hf = __uint_as_float(r << 16);
      const float lf = f[jj] - hf;
      const unsigned int u2 = __float_as_uint(lf);
      const unsigned int r2 = (u2 + 0x7FFFu + ((u2 >> 16) & 1u)) >> 16;
      ll[jj] = (unsigned short)r2;
    }
    ushort4 hv, lv;
    hv.x = hh[0]; hv.y = hh[1]; hv.z = hh[2]; hv.w = hh[3];
    lv.x = ll[0]; lv.y = ll[1]; lv.z = ll[2]; lv.w = ll[3];
    ((ushort4*)hi)[i] = hv;
    ((ushort4*)lo)[i] = lv;
  }
}

// ---------------------------------------------------------------------------
// Generic split-bf16 MFMA GEMM: C[m][n] = A[m]·B[n] + bias[n], 3-product
// (hi·hi + hi·lo + lo·hi), fp32 accum. Optional concat-A (A2/ksplit),
// optional tanh, OUT: 0 = fp32 C, 2 = bf16 hi/lo split outputs.
// Block 256 thr = 4 m-stacked waves; tile 128m x 64n; B staged in LDS.
// ---------------------------------------------------------------------------
template<int ACT, int OUT>
__global__ __launch_bounds__(256) void gemm_mfma(
    const unsigned short* __restrict__ Ahi, const unsigned short* __restrict__ Alo,
    const unsigned short* __restrict__ A2hi, const unsigned short* __restrict__ A2lo,
    int ksplit,
    const unsigned short* __restrict__ Bhi, const unsigned short* __restrict__ Blo,
    float* __restrict__ C, unsigned short* __restrict__ outHi,
    unsigned short* __restrict__ outLo, const float* __restrict__ bias,
    int K, int lda, int ldb, int ldc)
{
  __shared__ unsigned short BsH[64 * 32];
  __shared__ unsigned short BsL[64 * 32];
  const int tid  = threadIdx.x;
  const int wid  = tid >> 6;
  const int lane = tid & 63;
  const int l15  = lane & 15;
  const int kg   = lane >> 4;
  const int m0   = (blockIdx.y << 7) + (wid << 5);
  const int n0   = blockIdx.x << 6;
  const int srow = tid >> 2;
  const int scol = (tid & 3) << 3;

  f32x4 acc[2][4];
  #pragma unroll
  for (int fm = 0; fm < 2; ++fm)
    #pragma unroll
    for (int fn = 0; fn < 4; ++fn)
      acc[fm][fn] = (f32x4){0.f, 0.f, 0.f, 0.f};

  for (int k0 = 0; k0 < K; k0 += 32) {
    __syncthreads();
    *(bf16x8*)&BsH[srow * 32 + scol] =
        *(const bf16x8*)(Bhi + (size_t)(n0 + srow) * ldb + k0 + scol);
    *(bf16x8*)&BsL[srow * 32 + scol] =
        *(const bf16x8*)(Blo + (size_t)(n0 + srow) * ldb + k0 + scol);
    __syncthreads();

    const unsigned short* baseH = Ahi;
    const unsigned short* baseL = Alo;
    int keff = k0;
    if (A2hi != nullptr && k0 >= ksplit) {
      baseH = A2hi; baseL = A2lo; keff = k0 - ksplit;
    }
    bf16x8 ah[2], al[2];
    #pragma unroll
    for (int fm = 0; fm < 2; ++fm) {
      const size_t ro = (size_t)(m0 + (fm << 4) + l15) * lda + keff + (kg << 3);
      ah[fm] = *(const bf16x8*)(baseH + ro);
      al[fm] = *(const bf16x8*)(baseL + ro);
    }
    #pragma unroll
    for (int fm = 0; fm < 2; ++fm) {
      #pragma unroll
      for (int fn = 0; fn < 4; ++fn) {
        const bf16x8 bh  = *(const bf16x8*)&BsH[(((fn << 4) + l15) << 5) + (kg << 3)];
        const bf16x8 blv = *(const bf16x8*)&BsL[(((fn << 4) + l15) << 5) + (kg << 3)];
        acc[fm][fn] = __builtin_amdgcn_mfma_f32_16x16x32_bf16(
            ah[fm], bh, acc[fm][fn], 0, 0, 0);
        acc[fm][fn] = __builtin_amdgcn_mfma_f32_16x16x32_bf16(
            ah[fm], blv, acc[fm][fn], 0, 0, 0);
        acc[fm][fn] = __builtin_amdgcn_mfma_f32_16x16x32_bf16(
            al[fm], bh, acc[fm][fn], 0, 0, 0);
      }
    }
  }

  // epilogue: D col=l15, row=kg*4+reg (m89-verified)
  #pragma unroll
  for (int fm = 0; fm < 2; ++fm) {
    #pragma unroll
    for (int fn = 0; fn < 4; ++fn) {
      const int n = n0 + (fn << 4) + l15;
      const float bb = bias ? bias[n] : 0.0f;
      #pragma unroll
      for (int rg = 0; rg < 4; ++rg) {
        const int m = m0 + (fm << 4) + (kg << 2) + rg;
        float v = acc[fm][fn][rg] + bb;
        if (ACT == 1) v = tanhf(v);
        if (OUT == 2) {
          const unsigned int u = __float_as_uint(v);
          const unsigned int rv = (u + 0x7FFFu + ((u >> 16) & 1u)) >> 16;
          const float hf = __uint_as_float(rv << 16);
          const float lf = v - hf;
          const unsigned int u2 = __float_as_uint(lf);
          const unsigned int rl = (u2 + 0x7FFFu + ((u2 >> 16) & 1u)) >> 16;
          outHi[(size_t)m * ldc + n] = (unsigned short)rv;
          outLo[(size_t)m * ldc + n] = (unsigned short)rl;
        } else {
          C[(size_t)m * ldc + n] = v;
        }
      }
    }
  }
}

// ---------------------------------------------------------------------------
// Split-bf16 MFMA logits GEMM (proven R13 kernel, unchanged).
// C[(m&31)*NT+(m>>5)][n] = hid[m]·W2[n] + b2[n].
// ---------------------------------------------------------------------------
__global__ __launch_bounds__(256) void gemm_mfma_logits(
    const unsigned short* __restrict__ Ahi, const unsigned short* __restrict__ Alo,
    const unsigned short* __restrict__ Bhi, const unsigned short* __restrict__ Blo,
    float* __restrict__ C, const float* __restrict__ bias)
{
  __shared__ unsigned short BsH[64 * 32];   // [n-local][k-local]
  __shared__ unsigned short BsL[64 * 32];
  const int tid  = threadIdx.x;
  const int wid  = tid >> 6;        // wave 0..3 (m-stacked)
  const int lane = tid & 63;
  const int l15  = lane & 15;
  const int kg   = lane >> 4;       // 0..3
  const int m0   = (blockIdx.y << 7) + (wid << 5);  // wave's 32-row m base
  const int n0   = blockIdx.x << 6;

  const size_t aoff = (size_t)(m0 + l15) * NH + (kg << 3);
  const int srow = tid >> 2;        // staging: 64 rows, 4 thr/row
  const int scol = (tid & 3) << 3;  // 8-ushort chunks

  f32x4 acc[2][4];
  #pragma unroll
  for (int fm = 0; fm < 2; ++fm)
    #pragma unroll
    for (int fn = 0; fn < 4; ++fn)
      acc[fm][fn] = (f32x4){0.f, 0.f, 0.f, 0.f};

  for (int k0 = 0; k0 < NH; k0 += 32) {
    __syncthreads();  // prior iteration's LDS reads complete
    *(bf16x8*)&BsH[srow * 32 + scol] =
        *(const bf16x8*)(Bhi + (size_t)(n0 + srow) * NH + k0 + scol);
    *(bf16x8*)&BsL[srow * 32 + scol] =
        *(const bf16x8*)(Blo + (size_t)(n0 + srow) * NH + k0 + scol);
    __syncthreads();

    bf16x8 ah[2], al[2];
    #pragma unroll
    for (int fm = 0; fm < 2; ++fm) {
      ah[fm] = *(const bf16x8*)(Ahi + aoff + (size_t)(fm << 4) * NH + k0);
      al[fm] = *(const bf16x8*)(Alo + aoff + (size_t)(fm << 4) * NH + k0);
    }
    #pragma unroll
    for (int fm = 0; fm < 2; ++fm) {
      #pragma unroll
      for (int fn = 0; fn < 4; ++fn) {
        const bf16x8 bh  = *(const bf16x8*)&BsH[(((fn << 4) + l15) << 5) + (kg << 3)];
        const bf16x8 blv = *(const bf16x8*)&BsL[(((fn << 4) + l15) << 5) + (kg << 3)];
        acc[fm][fn] = __builtin_amdgcn_mfma_f32_16x16x32_bf16(
            ah[fm], bh, acc[fm][fn], 0, 0, 0);
        acc[fm][fn] = __builtin_amdgcn_mfma_f32_16x16x32_bf16(
            ah[fm], blv, acc[fm][fn], 0, 0, 0);
        acc[fm][fn] = __builtin_amdgcn_mfma_f32_16x16x32_bf16(
            al[fm], bh, acc[fm][fn], 0, 0, 0);
      }
    }
  }

  // epilogue: D col=l15, row=kg*4+reg; CSWAP (t*B+b) -> (b*T+t)
  #pragma unroll
  for (int fm = 0; fm < 2; ++fm) {
    #pragma unroll
    for (int fn = 0; fn < 4; ++fn) {
      const int n = n0 + (fn << 4) + l15;
      const float bb = bias[n];
      #pragma unroll
      for (int rg = 0; rg < 4; ++rg) {
        const int m = m0 + (fm << 4) + (kg << 2) + rg;
        const long orow = (long)(m & (NB - 1)) * NT + (m >> 5);
        C[orow * NVE + n] = acc[fm][fn][rg] + bb;
      }
    }
  }
}

// softmax over S=128 per (t,b) row, in place
__global__ __launch_bounds__(128) void softmax_s(float* __restrict__ sc) {
  const long row = blockIdx.x;
  float* p = sc + row * NS;
  const float x = p[threadIdx.x];
  float mx = x;
  for (int o = 32; o; o >>= 1) mx = fmaxf(mx, __shfl_xor(mx, o));
  __shared__ float r0[2], r1[2];
  const int w = threadIdx.x >> 6;
  if ((threadIdx.x & 63) == 0) r0[w] = mx;
  __syncthreads();
  mx = fmaxf(r0[0], r0[1]);
  const float e = expf(x - mx);
  float sum = e;
  for (int o = 32; o; o >>= 1) sum += __shfl_xor(sum, o);
  if ((threadIdx.x & 63) == 0) r1[w] = sum;
  __syncthreads();
  sum = r1[0] + r1[1];
  p[threadIdx.x] = e / sum;
}

// softmax over VE=8000 per (b,t) row of d_out, in place
__global__ __launch_bounds__(256) void softmax_v(float* __restrict__ out) {
  const long row = blockIdx.x;
  float* p = out + row * NVE;
  float v[32];
  float mx = -1e30f;
  #pragma unroll
  for (int it = 0; it < 32; ++it) {
    const int idx = (it << 8) + threadIdx.x;
    v[it] = (idx < NVE) ? p[idx] : -1e30f;
    mx = fmaxf(mx, v[it]);
  }
  for (int o = 32; o; o >>= 1) mx = fmaxf(mx, __shfl_xor(mx, o));
  __shared__ float red[4], red2[4];
  const int w = threadIdx.x >> 6;
  if ((threadIdx.x & 63) == 0) red[w] = mx;
  __syncthreads();
  mx = fmaxf(fmaxf(red[0], red[1]), fmaxf(red[2], red[3]));
  float sum = 0.0f;
  #pragma unroll
  for (int it = 0; it < 32; ++it) {
    const int idx = (it << 8) + threadIdx.x;
    if (idx < NVE) { v[it] = expf(v[it] - mx); sum += v[it]; }
  }
  for (int o = 32; o; o >>= 1) sum += __shfl_xor(sum, o);
  if ((threadIdx.x & 63) == 0) red2[w] = sum;
  __syncthreads();
  sum = red2[0] + red2[1] + red2[2] + red2[3];
  const float inv = 1.0f / sum;
  #pragma unroll
  for (int it = 0; it < 32; ++it) {
    const int idx = (it << 8) + threadIdx.x;
    if (idx < NVE) p[idx] = v[it] * inv;
  }
}

extern "C" void kernel_launch(void* const* d_in, const int* in_sizes, int n_in,
                              void* d_out, int out_size, void* d_ws, size_t ws_size,
                              hipStream_t stream) {
  const int*   in_tok = (const int*)d_in[0];
  const int*   out_tok = (const int*)d_in[1];
  const float* Wa    = (const float*)d_in[2];
  const float* ba    = (const float*)d_in[3];
  const float* W1    = (const float*)d_in[4];
  const float* b1    = (const float*)d_in[5];
  const float* W2    = (const float*)d_in[6];
  const float* b2    = (const float*)d_in[7];
  const float* We_ih = (const float*)d_in[8];
  const float* We_hh = (const float*)d_in[9];
  const float* be_ih = (const float*)d_in[10];
  const float* be_hh = (const float*)d_in[11];
  const float* Wd_ih = (const float*)d_in[12];
  const float* Wd_hh = (const float*)d_in[13];
  const float* bd_ih = (const float*)d_in[14];
  const float* bd_hh = (const float*)d_in[15];

  float* ws      = (float*)d_ws;
  float* h_buf   = ws;                 // [0, 32768)
  float* enc_out = ws + 32768;         // [32768, 2129920)
  float* dec_h   = ws + 2129920;       // [2129920, 4227072)
  float* proj    = ws + 4227072;       // [4227072, 6324224)
  float* scores  = ws + 6324224;       // [6324224, 6848512)
  float* ctx     = ws + 6848512;       // [6848512, 8945664)
  // spare (old hid region): [8945664, 11042816)
  int*   flags   = (int*)(ws + 11042816);  // 256 ints
  float* out     = (float*)d_out;

  // bf16 hi/lo aliases, sequenced so no live ranges overlap:
  unsigned short* eo_hi  = (unsigned short*)(ws + 8945664);            // spare
  unsigned short* eo_lo  = (unsigned short*)(ws + 8945664 + 1048576);
  unsigned short* wa_hi  = (unsigned short*)(ws + 6324224);            // scores (pre-step3)
  unsigned short* wa_lo  = (unsigned short*)(ws + 6324224 + 131072);
  unsigned short* w1_hi  = (unsigned short*)(ws + 4227072);            // proj (post-step3)
  unsigned short* w1_lo  = (unsigned short*)(ws + 4227072 + 262144);
  unsigned short* dh_hi  = (unsigned short*)(ws + 32768);              // enc_out (post-step5)
  unsigned short* dh_lo  = (unsigned short*)(ws + 32768 + 1048576);
  unsigned short* cx_hi  = (unsigned short*)(ws + 2129920);            // dec_h (post dh-split)
  unsigned short* cx_lo  = (unsigned short*)(ws + 2129920 + 1048576);
  unsigned short* hid_hi = (unsigned short*)(ws + 6848512);            // ctx (post cx-split)
  unsigned short* hid_lo = (unsigned short*)(ws + 6848512 + 1048576);
  unsigned short* w2_hi  = (unsigned short*)(ws + 8945664);            // spare (post-step6)
  unsigned short* w2_lo  = (unsigned short*)(ws + 32768);              // enc_out (post-step6)

  (void)hipMemsetAsync((void*)flags, 0, 256 * sizeof(int), stream);

  // 1. encoder + decoder-LSTM scan (R5-verbatim)
  {
    void* args[14];
    args[0] = (void*)&in_tok; args[1] = (void*)&out_tok;
    args[2] = (void*)&We_ih;  args[3] = (void*)&We_hh;
    args[4] = (void*)&be_ih;  args[5] = (void*)&be_hh;
    args[6] = (void*)&Wd_ih;  args[7] = (void*)&Wd_hh;
    args[8] = (void*)&bd_ih;  args[9] = (void*)&bd_hh;
    args[10] = (void*)&h_buf; args[11] = (void*)&enc_out; args[12] = (void*)&dec_h;
    args[13] = (void*)&flags;
    (void)hipLaunchCooperativeKernel((void*)scan_kernel, dim3(256), dim3(256), args, 0, stream);
  }

  // 2a. splits for proj GEMM
  split_bf16<<<dim3(2048), 256, 0, stream>>>(enc_out, eo_hi, eo_lo, 524288);
  split_bf16<<<dim3(512), 256, 0, stream>>>(Wa, wa_hi, wa_lo, 65536);

  // 2b. proj = enc_out @ Wa^T + ba   [4096,512] K=512 (split-bf16 MFMA)
  gemm_mfma<0, 0><<<dim3(8, 32), 256, 0, stream>>>(
      eo_hi, eo_lo, nullptr, nullptr, 1 << 30,
      wa_hi, wa_lo, proj, nullptr, nullptr, ba,
      512, 512, 512, 512);

  // 3. scores[t,b,s] = dec_h . proj_enc (batched over b)   M=T,N=S,K=H (fp32)
  gemm64<0,0,0><<<dim3(2,2,NB), 256, 0, stream>>>(
      dec_h, proj, scores, nullptr, nullptr, 1 << 30,
      NT, NS, NH, NB * NH, NB * NH, NB * NS,
      (long)NH, (long)NH, (long)NS);

  // 4. softmax over s
  softmax_s<<<dim3(NT * NB), 128, 0, stream>>>(scores);

  // 4b. split W1 (proj region free after step 3)
  split_bf16<<<dim3(1024), 256, 0, stream>>>(W1, w1_hi, w1_lo, 131072);

  // 5. context[t,b,h] = w @ enc_out (batched over b, B is [K][N])  (fp32)
  gemm64<1,0,0><<<dim3(8,2,NB), 256, 0, stream>>>(
      scores, enc_out, ctx, nullptr, nullptr, 1 << 30,
      NT, NH, NS, NB * NS, NB * NH, NB * NH,
      (long)NS, (long)NH, (long)NH);

  // 5b. split dec_h (into enc_out region) then ctx (into dec_h region)
  split_bf16<<<dim3(2048), 256, 0, stream>>>(dec_h, dh_hi, dh_lo, 524288);
  split_bf16<<<dim3(2048), 256, 0, stream>>>(ctx, cx_hi, cx_lo, 524288);

  // 6. hid = tanh(concat(dec_h, ctx) @ W1^T + b1) -> bf16 hi/lo (MFMA)
  gemm_mfma<1, 2><<<dim3(8, 32), 256, 0, stream>>>(
      dh_hi, dh_lo, cx_hi, cx_lo, 512,
      w1_hi, w1_lo, nullptr, hid_hi, hid_lo, b1,
      1024, 512, 1024, 512);

  // 6b. split W2 (spare + enc_out regions free after step 6)
  split_bf16<<<dim3(2048), 256, 0, stream>>>(W2, w2_hi, w2_lo, 1024000);

  // 7. logits = hid @ W2^T + b2 -> d_out[b][t][v]  via split-bf16 MFMA
  gemm_mfma_logits<<<dim3(125, 32), 256, 0, stream>>>(
      hid_hi, hid_lo, w2_hi, w2_lo, out, b2);

  // 8. softmax over vocab, in place on d_out
  softmax_v<<<dim3(NB * NT), 256, 0, stream>>>(out);
}